// Round 10
// baseline (122.240 us; speedup 1.0000x reference)
//
#include <hip/hip_runtime.h>
#include <hip/hip_bf16.h>

#define OUTF 4096
#define INF  4096
#define BATCH 128
#define NBIN 1024     // (r>>4: 256) x (c>>10: 4)
#define NCELL 1024    // bin-writer blocks; cell = (cellcol, bin), lambda = 1
#define CAP  16       // P(cell > 16 | lambda=1) ~ 2e-14; E[overflows] ~ 2e-8
#define SQ   1028     // strip row stride (1024 + 4 pad)

typedef _Float16 f16x8 __attribute__((ext_vector_type(8)));
typedef float    f32x4 __attribute__((ext_vector_type(4)));

// Xh fp16 tiled: [kt(128)][nt(8)][n(16)][k(32)] -> tile = 512 halfs = 1KB

// ---- fused: blocks [0,NCELL) bin the COO; blocks [NCELL, NCELL+256) cvt X ----
// Cells are (cellcol=blk)-private -> zero global atomics, no line bouncing.
__global__ __launch_bounds__(256) void k_prep(const float* __restrict__ X,
                                              const float* __restrict__ vals,
                                              const int* __restrict__ rows,
                                              const int* __restrict__ cols, int nnz,
                                              _Float16* __restrict__ Xh,
                                              int2* __restrict__ bucket,
                                              int* __restrict__ cnts) {
  __shared__ int cnt[NBIN];
  const int t = threadIdx.x;
  const int blk = blockIdx.x;
  if (blk < NCELL) {
    for (int b = t; b < NBIN; b += 256) cnt[b] = 0;
    __syncthreads();
    const int G4 = nnz >> 2;
    const int g = blk * 256 + t;
    if (g < G4) {
      int4   r4 = ((const int4*)rows)[g];
      int4   c4 = ((const int4*)cols)[g];
      float4 v4 = ((const float4*)vals)[g];
      int rr[4] = {r4.x, r4.y, r4.z, r4.w};
      int cc[4] = {c4.x, c4.y, c4.z, c4.w};
      float vv[4] = {v4.x, v4.y, v4.z, v4.w};
#pragma unroll
      for (int j = 0; j < 4; ++j) {
        int bin = ((rr[j] >> 4) << 2) | (cc[j] >> 10);
        int slot = atomicAdd(&cnt[bin], 1);
        if (slot < CAP) {
          int2 e;
          e.x = __float_as_int(vv[j]);
          e.y = ((rr[j] & 15) << 10) | (cc[j] & 1023);
          bucket[((size_t)blk * NBIN + bin) * CAP + slot] = e;
        }
      }
    }
    if (blk == 0) {  // tail entries (nnz % 4) into block 0's cells
      for (int i = (nnz & ~3) + t; i < nnz; i += 256) {
        int r = rows[i], c = cols[i];
        int bin = ((r >> 4) << 2) | (c >> 10);
        int slot = atomicAdd(&cnt[bin], 1);
        if (slot < CAP) {
          int2 e;
          e.x = __float_as_int(vals[i]);
          e.y = ((r & 15) << 10) | (c & 1023);
          bucket[((size_t)blk * NBIN + bin) * CAP + slot] = e;
        }
      }
    }
    __syncthreads();
    for (int b = t; b < NBIN; b += 256)
      cnts[(size_t)blk * NBIN + b] = min(cnt[b], CAP);
  } else {
    // cvtX: 256 blocks x 256 threads x 8 elems = 128 x 4096
    int g = (blk - NCELL) * 256 + t;
    int n = g >> 9;
    int k0 = (g & 511) * 8;
    float4 f0 = *(const float4*)(X + (size_t)n * INF + k0);
    float4 f1 = *(const float4*)(X + (size_t)n * INF + k0 + 4);
    f16x8 h;
    h[0] = (_Float16)f0.x; h[1] = (_Float16)f0.y;
    h[2] = (_Float16)f0.z; h[3] = (_Float16)f0.w;
    h[4] = (_Float16)f1.x; h[5] = (_Float16)f1.y;
    h[6] = (_Float16)f1.z; h[7] = (_Float16)f1.w;
    size_t idx = ((size_t)(k0 >> 5) * 8 + (n >> 4)) * 512 + (n & 15) * 32 + (k0 & 31);
    *(f16x8*)(Xh + idx) = h;
  }
}

// ---- fused densify+GEMM per bin: build 16x1024 fp32 strip in LDS, MFMA vs
// tiled Xh, reduce the 4 wave-partials through LDS -> one slab (kq).
// LDS 65.8 KB -> 2 blocks/CU (__launch_bounds__(256,2)); 1024 blocks.
// Fragment maps (HW-validated R5/R6): A row=l&15,k=(l>>4)*8+j;
// B col=l&15,same k; C/D col=l&15,row=(l>>4)*4+i.
__global__ __launch_bounds__(256, 2) void k_strip(const int2* __restrict__ bucket,
                                                  const int* __restrict__ cnts,
                                                  const _Float16* __restrict__ Xh,
                                                  float* __restrict__ outP) {
  __shared__ float strip[16 * SQ];  // 65,792 B
  const int t = threadIdx.x;
  const int bin = blockIdx.x;
  const int mt = bin >> 2, kq = bin & 3;

  {  // zero
    float4 z = {0.f, 0.f, 0.f, 0.f};
    const int nvec = 16 * SQ / 4;  // 4112
    for (int j = t; j < nvec; j += 256) ((float4*)strip)[j] = z;
  }
  __syncthreads();

  // drain: thread handles cells (cellcol = t, t+256, t+512, t+768)
  for (int cc = t; cc < NCELL; cc += 256) {
    int cnt = cnts[(size_t)cc * NBIN + bin];
    const int2* cell = bucket + ((size_t)cc * NBIN + bin) * CAP;
    for (int j = 0; j < cnt; ++j) {
      int2 e = cell[j];
      atomicAdd(&strip[((e.y >> 10) & 15) * SQ + (e.y & 1023)], __int_as_float(e.x));
    }
  }
  __syncthreads();

  // MFMA: wave wid covers ktl = wid, wid+4, ..., 28+wid (8 iters x 8 nt)
  const int lane = t & 63, wid = t >> 6;
  const int lr = lane & 15, lg = lane >> 4;
  f32x4 acc[8] = {};
  for (int ktl = wid; ktl < 32; ktl += 4) {
    const int kt = kq * 32 + ktl;
    float4 alo = *(const float4*)&strip[lr * SQ + ktl * 32 + lg * 8];
    float4 ahi = *(const float4*)&strip[lr * SQ + ktl * 32 + lg * 8 + 4];
    f16x8 a;
    a[0] = (_Float16)alo.x; a[1] = (_Float16)alo.y;
    a[2] = (_Float16)alo.z; a[3] = (_Float16)alo.w;
    a[4] = (_Float16)ahi.x; a[5] = (_Float16)ahi.y;
    a[6] = (_Float16)ahi.z; a[7] = (_Float16)ahi.w;
    const _Float16* bp = Xh + (size_t)kt * 4096 + lr * 32 + lg * 8;
    f16x8 b[8];
#pragma unroll
    for (int nt = 0; nt < 8; ++nt) b[nt] = *(const f16x8*)(bp + nt * 512);
#pragma unroll
    for (int nt = 0; nt < 8; ++nt)
      acc[nt] = __builtin_amdgcn_mfma_f32_16x16x32_f16(a, b[nt], acc[nt], 0, 0, 0);
  }
  __syncthreads();  // strip reads done; reuse LDS as reduce buffer

  // wave partials -> LDS (red[wid][2048]) -> sum -> slab kq
  float* red = strip;
#pragma unroll
  for (int nt = 0; nt < 8; ++nt)
#pragma unroll
    for (int i = 0; i < 4; ++i)
      red[wid * 2048 + (lg * 4 + i) * 128 + nt * 16 + lr] = acc[nt][i];
  __syncthreads();
  float* op = outP + (size_t)kq * (OUTF * BATCH) + (size_t)mt * 2048;
  for (int e = t; e < 2048; e += 256)
    op[e] = red[e] + red[2048 + e] + red[4096 + e] + red[6144 + e];
}

// ---- merge 4 slabs [slab][4096 r][128 b] -> out[b][r], LDS transpose ----
__global__ __launch_bounds__(1024) void k_merge(const float* __restrict__ outP,
                                                float* __restrict__ out) {
  __shared__ float t[32][33];
  int bbase = blockIdx.x * 32;
  int rbase = blockIdx.y * 32;
  size_t src = (size_t)(rbase + threadIdx.y) * 128 + bbase + threadIdx.x;
  float s = outP[src] + outP[(size_t)OUTF * BATCH + src] +
            outP[(size_t)2 * OUTF * BATCH + src] + outP[(size_t)3 * OUTF * BATCH + src];
  t[threadIdx.y][threadIdx.x] = s;
  __syncthreads();
  out[(size_t)(bbase + threadIdx.y) * OUTF + rbase + threadIdx.x] = t[threadIdx.x][threadIdx.y];
}

// ---- safety-net fallback if ws is too small: direct atomics ----
__global__ __launch_bounds__(256) void k_fallback(const float* __restrict__ X,
                                                  const float* __restrict__ vals,
                                                  const int* __restrict__ rows,
                                                  const int* __restrict__ cols, int n,
                                                  float* __restrict__ out) {
  int k = blockIdx.x * blockDim.x + threadIdx.x;
  if (k >= n) return;
  float v = vals[k];
  int r = rows[k], c = cols[k];
  for (int b = 0; b < BATCH; ++b)
    atomicAdd(&out[(size_t)b * OUTF + r], v * X[(size_t)b * INF + c]);
}

extern "C" void kernel_launch(void* const* d_in, const int* in_sizes, int n_in,
                              void* d_out, int out_size, void* d_ws, size_t ws_size,
                              hipStream_t stream) {
  const float* X  = (const float*)d_in[0];
  const float* Wv = (const float*)d_in[1];
  const int*   Wr = (const int*)d_in[2];
  const int*   Wc = (const int*)d_in[3];
  float* out = (float*)d_out;
  const int nnz = in_sizes[1];

  char* ws = (char*)d_ws;
  const size_t OFF_XH   = 0;                                        // 1 MB
  const size_t OFF_BKT  = OFF_XH  + (size_t)BATCH * INF * 2;        // 134.2 MB
  const size_t OFF_CNT  = OFF_BKT + (size_t)NCELL * NBIN * CAP * 8; // 4 MB
  const size_t OFF_OUTP = OFF_CNT + (size_t)NCELL * NBIN * 4;       // 8 MB
  const size_t NEEDED   = OFF_OUTP + (size_t)4 * OUTF * BATCH * 4;  // ~147 MB

  if (ws_size < NEEDED) {
    hipMemsetAsync(d_out, 0, (size_t)out_size * 4, stream);
    k_fallback<<<dim3((nnz + 255) / 256), dim3(256), 0, stream>>>(X, Wv, Wr, Wc, nnz, out);
    return;
  }

  _Float16* Xh     = (_Float16*)(ws + OFF_XH);
  int2*     bucket = (int2*)(ws + OFF_BKT);
  int*      cnts   = (int*)(ws + OFF_CNT);
  float*    outP   = (float*)(ws + OFF_OUTP);

  k_prep<<<dim3(NCELL + 256), dim3(256), 0, stream>>>(X, Wv, Wr, Wc, nnz, Xh, bucket, cnts);
  k_strip<<<dim3(NBIN), dim3(256), 0, stream>>>(bucket, cnts, Xh, outP);
  k_merge<<<dim3(BATCH / 32, OUTF / 32), dim3(32, 32), 0, stream>>>(outP, out);
}

// Round 11
// 114.730 us; speedup vs baseline: 1.0655x; 1.0655x over previous
//
#include <hip/hip_runtime.h>
#include <hip/hip_bf16.h>

#define OUTF 4096
#define INF  4096
#define BATCH 128
#define NBIN 1024     // (mt: 256) x (kq: 4)
#define CHUNK 1024    // entries per writer block
#define SEGP (NBIN + 1)
#define SQ   1028     // strip row stride (1024 + 4 pad)

typedef _Float16 f16x8 __attribute__((ext_vector_type(8)));
typedef float    f32x4 __attribute__((ext_vector_type(4)));

// Xh fp16 tiled: [kt(128)][nt(8)][n(16)][k(32)] -> tile = 512 halfs = 1KB

// ---- fused: blocks [0,nw) sort their COO chunk by bin (dense bucket);
//      blocks [nw, nw+256) convert X -> tiled fp16.
// Writer block: LDS hist -> block scan -> LDS-cursor scatter into LDS staging
// -> fully coalesced 8KB run write. Zero global atomics, zero waste.
__global__ __launch_bounds__(256) void k_prep(const float* __restrict__ X,
                                              const float* __restrict__ vals,
                                              const int* __restrict__ rows,
                                              const int* __restrict__ cols,
                                              int nnz, int nw,
                                              _Float16* __restrict__ Xh,
                                              int2* __restrict__ bucket,
                                              int* __restrict__ segStart) {
  __shared__ int  hist[NBIN];    // 4 KB (becomes cursor)
  __shared__ int  scanT[256];    // 1 KB
  __shared__ int2 stage[CHUNK];  // 8 KB
  const int t = threadIdx.x;
  const int blk = blockIdx.x;

  if (blk < nw) {
    const int s = blk * CHUNK;
    const int e = min(nnz, s + CHUNK);
    const int cnt = e - s;
    for (int b = t; b < NBIN; b += 256) hist[b] = 0;
    __syncthreads();

    int   bins[4], metas[4];
    float vv[4];
    int   nloc = 0;
    if (s + 4 * t + 3 < e) {  // full int4 group
      int g = (s >> 2) + t;
      int4   r4 = ((const int4*)rows)[g];
      int4   c4 = ((const int4*)cols)[g];
      float4 v4 = ((const float4*)vals)[g];
      int rr[4] = {r4.x, r4.y, r4.z, r4.w};
      int cc[4] = {c4.x, c4.y, c4.z, c4.w};
      float vf[4] = {v4.x, v4.y, v4.z, v4.w};
#pragma unroll
      for (int j = 0; j < 4; ++j) {
        bins[j]  = ((rr[j] >> 4) << 2) | (cc[j] >> 10);
        metas[j] = ((rr[j] & 15) << 10) | (cc[j] & 1023);
        vv[j] = vf[j];
        atomicAdd(&hist[bins[j]], 1);
      }
      nloc = 4;
    } else {
      for (int i = s + 4 * t; i < e; ++i) {
        int r = rows[i], c = cols[i];
        bins[nloc]  = ((r >> 4) << 2) | (c >> 10);
        metas[nloc] = ((r & 15) << 10) | (c & 1023);
        vv[nloc] = vals[i];
        atomicAdd(&hist[bins[nloc]], 1);
        ++nloc;
      }
    }
    __syncthreads();

    // scan over 1024 bins: thread t owns bins 4t..4t+3
    const int base = t * 4;
    int l0 = hist[base], l1 = hist[base + 1], l2 = hist[base + 2], l3 = hist[base + 3];
    int sum = l0 + l1 + l2 + l3;
    scanT[t] = sum;
    __syncthreads();
    for (int off = 1; off < 256; off <<= 1) {
      int u = (t >= off) ? scanT[t - off] : 0;
      __syncthreads();
      scanT[t] += u;
      __syncthreads();
    }
    int excl = scanT[t] - sum;
    int st0 = excl, st1 = excl + l0, st2 = st1 + l1, st3 = st2 + l2;
    int* sp = segStart + (size_t)blk * SEGP + base;
    sp[0] = st0; sp[1] = st1; sp[2] = st2; sp[3] = st3;
    hist[base] = st0; hist[base + 1] = st1; hist[base + 2] = st2; hist[base + 3] = st3;
    if (t == 255) segStart[(size_t)blk * SEGP + NBIN] = cnt;
    __syncthreads();

    // scatter into staging via LDS cursors
    for (int j = 0; j < nloc; ++j) {
      int slot = atomicAdd(&hist[bins[j]], 1);
      int2 ent;
      ent.x = __float_as_int(vv[j]);
      ent.y = metas[j];
      stage[slot] = ent;
    }
    __syncthreads();

    // coalesced run write
    for (int i = t; i < cnt; i += 256) bucket[s + i] = stage[i];
  } else {
    // cvtX: 256 blocks x 256 threads x 8 elems = 128 x 4096
    int g = (blk - nw) * 256 + t;
    int n = g >> 9;
    int k0 = (g & 511) * 8;
    float4 f0 = *(const float4*)(X + (size_t)n * INF + k0);
    float4 f1 = *(const float4*)(X + (size_t)n * INF + k0 + 4);
    f16x8 h;
    h[0] = (_Float16)f0.x; h[1] = (_Float16)f0.y;
    h[2] = (_Float16)f0.z; h[3] = (_Float16)f0.w;
    h[4] = (_Float16)f1.x; h[5] = (_Float16)f1.y;
    h[6] = (_Float16)f1.z; h[7] = (_Float16)f1.w;
    size_t idx = ((size_t)(k0 >> 5) * 8 + (n >> 4)) * 512 + (n & 15) * 32 + (k0 & 31);
    *(f16x8*)(Xh + idx) = h;
  }
}

// ---- fused densify+GEMM per bin: drain dense bucket segments into a
// 16x1024 fp32 LDS strip (LDS atomics), MFMA vs tiled Xh, reduce 4 wave
// partials through LDS -> slab kq. LDS 65.8 KB -> 2 blocks/CU.
// Fragment maps (HW-validated R5/R6): A row=l&15,k=(l>>4)*8+j;
// B col=l&15,same k; C/D col=l&15,row=(l>>4)*4+i.
__global__ __launch_bounds__(256, 2) void k_strip(const int2* __restrict__ bucket,
                                                  const int* __restrict__ segStart,
                                                  int nw,
                                                  const _Float16* __restrict__ Xh,
                                                  float* __restrict__ outP) {
  __shared__ float strip[16 * SQ];  // 65,792 B
  const int t = threadIdx.x;
  const int bin = blockIdx.x;
  const int mt = bin >> 2, kq = bin & 3;

  {  // zero
    float4 z = {0.f, 0.f, 0.f, 0.f};
    const int nvec = 16 * SQ / 4;  // 4112
    for (int j = t; j < nvec; j += 256) ((float4*)strip)[j] = z;
  }
  __syncthreads();

  // drain: thread t handles writer chunks t, t+256, t+512, t+768
  for (int cc = t; cc < nw; cc += 256) {
    const int* sp = segStart + (size_t)cc * SEGP + bin;
    int sbase = sp[0];
    int send  = sp[1];
    const int2* p = bucket + (size_t)cc * CHUNK;
    for (int j = sbase; j < send; ++j) {
      int2 e = p[j];
      atomicAdd(&strip[((e.y >> 10) & 15) * SQ + (e.y & 1023)], __int_as_float(e.x));
    }
  }
  __syncthreads();

  // MFMA: wave wid covers ktl = wid, wid+4, ..., 28+wid (8 iters x 8 nt)
  const int lane = t & 63, wid = t >> 6;
  const int lr = lane & 15, lg = lane >> 4;
  f32x4 acc[8] = {};
  for (int ktl = wid; ktl < 32; ktl += 4) {
    const int kt = kq * 32 + ktl;
    float4 alo = *(const float4*)&strip[lr * SQ + ktl * 32 + lg * 8];
    float4 ahi = *(const float4*)&strip[lr * SQ + ktl * 32 + lg * 8 + 4];
    f16x8 a;
    a[0] = (_Float16)alo.x; a[1] = (_Float16)alo.y;
    a[2] = (_Float16)alo.z; a[3] = (_Float16)alo.w;
    a[4] = (_Float16)ahi.x; a[5] = (_Float16)ahi.y;
    a[6] = (_Float16)ahi.z; a[7] = (_Float16)ahi.w;
    const _Float16* bp = Xh + (size_t)kt * 4096 + lr * 32 + lg * 8;
    f16x8 b[8];
#pragma unroll
    for (int nt = 0; nt < 8; ++nt) b[nt] = *(const f16x8*)(bp + nt * 512);
#pragma unroll
    for (int nt = 0; nt < 8; ++nt)
      acc[nt] = __builtin_amdgcn_mfma_f32_16x16x32_f16(a, b[nt], acc[nt], 0, 0, 0);
  }
  __syncthreads();  // strip reads done; reuse LDS as reduce buffer

  float* red = strip;
#pragma unroll
  for (int nt = 0; nt < 8; ++nt)
#pragma unroll
    for (int i = 0; i < 4; ++i)
      red[wid * 2048 + (lg * 4 + i) * 128 + nt * 16 + lr] = acc[nt][i];
  __syncthreads();
  float* op = outP + (size_t)kq * (OUTF * BATCH) + (size_t)mt * 2048;
  for (int e = t; e < 2048; e += 256)
    op[e] = red[e] + red[2048 + e] + red[4096 + e] + red[6144 + e];
}

// ---- merge 4 slabs [slab][4096 r][128 b] -> out[b][r], LDS transpose ----
__global__ __launch_bounds__(1024) void k_merge(const float* __restrict__ outP,
                                                float* __restrict__ out) {
  __shared__ float t[32][33];
  int bbase = blockIdx.x * 32;
  int rbase = blockIdx.y * 32;
  size_t src = (size_t)(rbase + threadIdx.y) * 128 + bbase + threadIdx.x;
  float s = outP[src] + outP[(size_t)OUTF * BATCH + src] +
            outP[(size_t)2 * OUTF * BATCH + src] + outP[(size_t)3 * OUTF * BATCH + src];
  t[threadIdx.y][threadIdx.x] = s;
  __syncthreads();
  out[(size_t)(bbase + threadIdx.y) * OUTF + rbase + threadIdx.x] = t[threadIdx.x][threadIdx.y];
}

// ---- safety-net fallback if ws is too small: direct atomics ----
__global__ __launch_bounds__(256) void k_fallback(const float* __restrict__ X,
                                                  const float* __restrict__ vals,
                                                  const int* __restrict__ rows,
                                                  const int* __restrict__ cols, int n,
                                                  float* __restrict__ out) {
  int k = blockIdx.x * blockDim.x + threadIdx.x;
  if (k >= n) return;
  float v = vals[k];
  int r = rows[k], c = cols[k];
  for (int b = 0; b < BATCH; ++b)
    atomicAdd(&out[(size_t)b * OUTF + r], v * X[(size_t)b * INF + c]);
}

extern "C" void kernel_launch(void* const* d_in, const int* in_sizes, int n_in,
                              void* d_out, int out_size, void* d_ws, size_t ws_size,
                              hipStream_t stream) {
  const float* X  = (const float*)d_in[0];
  const float* Wv = (const float*)d_in[1];
  const int*   Wr = (const int*)d_in[2];
  const int*   Wc = (const int*)d_in[3];
  float* out = (float*)d_out;
  const int nnz = in_sizes[1];
  const int nw = (nnz + CHUNK - 1) / CHUNK;  // 1024 for nnz = 1M

  char* ws = (char*)d_ws;
  const size_t OFF_XH   = 0;                                       // 1 MB
  const size_t OFF_BKT  = OFF_XH  + (size_t)BATCH * INF * 2;       // nnz*8 = 8 MB
  const size_t OFF_SEG  = OFF_BKT + (size_t)nw * CHUNK * 8;        // nw*SEGP*4 ~ 4.2 MB
  const size_t OFF_OUTP = OFF_SEG + (size_t)nw * SEGP * 4;         // 8 MB
  const size_t NEEDED   = OFF_OUTP + (size_t)4 * OUTF * BATCH * 4; // ~21.5 MB

  if (ws_size < NEEDED) {
    hipMemsetAsync(d_out, 0, (size_t)out_size * 4, stream);
    k_fallback<<<dim3((nnz + 255) / 256), dim3(256), 0, stream>>>(X, Wv, Wr, Wc, nnz, out);
    return;
  }

  _Float16* Xh       = (_Float16*)(ws + OFF_XH);
  int2*     bucket   = (int2*)(ws + OFF_BKT);
  int*      segStart = (int*)(ws + OFF_SEG);
  float*    outP     = (float*)(ws + OFF_OUTP);

  k_prep<<<dim3(nw + 256), dim3(256), 0, stream>>>(X, Wv, Wr, Wc, nnz, nw, Xh, bucket, segStart);
  k_strip<<<dim3(NBIN), dim3(256), 0, stream>>>(bucket, segStart, nw, Xh, outP);
  k_merge<<<dim3(BATCH / 32, OUTF / 32), dim3(32, 32), 0, stream>>>(outP, out);
}

// Round 12
// 110.326 us; speedup vs baseline: 1.1080x; 1.0399x over previous
//
#include <hip/hip_runtime.h>
#include <hip/hip_bf16.h>

#define OUTF 4096
#define INF  4096
#define BATCH 128
#define NBIN 1024     // (mt: 256) x (kq: 4)
#define CHUNK 4096    // entries per writer block (lambda=4 per (chunk,bin))
#define SEGP (NBIN + 1)
#define SQ   1028     // strip row stride (1024 + 4 pad)

typedef _Float16 f16x8 __attribute__((ext_vector_type(8)));
typedef float    f32x4 __attribute__((ext_vector_type(4)));

// Xh fp16 tiled: [kt(128)][nt(8)][n(16)][k(32)] -> tile = 512 halfs = 1KB

// ---- fused: blocks [0,nw) sort their 4096-entry COO chunk by bin (dense
// bucket); blocks [nw, nw+256) convert X -> tiled fp16.
// Writer block: LDS hist -> block scan -> LDS-cursor scatter into LDS staging
// -> fully coalesced 32KB run write. Zero global atomics.
__global__ __launch_bounds__(256) void k_prep(const float* __restrict__ X,
                                              const float* __restrict__ vals,
                                              const int* __restrict__ rows,
                                              const int* __restrict__ cols,
                                              int nnz, int nw,
                                              _Float16* __restrict__ Xh,
                                              int2* __restrict__ bucket,
                                              int* __restrict__ segStart) {
  __shared__ int  hist[NBIN];     // 4 KB (becomes cursor)
  __shared__ int  scanT[256];     // 1 KB
  __shared__ int2 stage[CHUNK];   // 32 KB
  const int t = threadIdx.x;
  const int blk = blockIdx.x;

  if (blk < nw) {
    const int s = blk * CHUNK;
    const int e = min(nnz, s + CHUNK);
    const int cnt = e - s;
    for (int b = t; b < NBIN; b += 256) hist[b] = 0;
    __syncthreads();

    // 16 entries/thread: 4 int4 groups at stride-256 (coalesced)
    int   bins[16], metas[16];
    float vv[16];
    int   nloc = 0;
#pragma unroll
    for (int j = 0; j < 4; ++j) {
      int gi = s + (j * 256 + t) * 4;  // group base index
      if (gi + 3 < e) {
        int g = gi >> 2;
        int4   r4 = ((const int4*)rows)[g];
        int4   c4 = ((const int4*)cols)[g];
        float4 v4 = ((const float4*)vals)[g];
        int rr[4] = {r4.x, r4.y, r4.z, r4.w};
        int cc[4] = {c4.x, c4.y, c4.z, c4.w};
        float vf[4] = {v4.x, v4.y, v4.z, v4.w};
#pragma unroll
        for (int q = 0; q < 4; ++q) {
          bins[nloc]  = ((rr[q] >> 4) << 2) | (cc[q] >> 10);
          metas[nloc] = ((rr[q] & 15) << 10) | (cc[q] & 1023);
          vv[nloc] = vf[q];
          atomicAdd(&hist[bins[nloc]], 1);
          ++nloc;
        }
      } else {
        for (int i = gi; i < e; ++i) {  // ragged tail (last block only)
          int r = rows[i], c = cols[i];
          bins[nloc]  = ((r >> 4) << 2) | (c >> 10);
          metas[nloc] = ((r & 15) << 10) | (c & 1023);
          vv[nloc] = vals[i];
          atomicAdd(&hist[bins[nloc]], 1);
          ++nloc;
        }
      }
    }
    __syncthreads();

    // scan over 1024 bins: thread t owns bins 4t..4t+3
    const int base = t * 4;
    int l0 = hist[base], l1 = hist[base + 1], l2 = hist[base + 2], l3 = hist[base + 3];
    int sum = l0 + l1 + l2 + l3;
    scanT[t] = sum;
    __syncthreads();
    for (int off = 1; off < 256; off <<= 1) {
      int u = (t >= off) ? scanT[t - off] : 0;
      __syncthreads();
      scanT[t] += u;
      __syncthreads();
    }
    int excl = scanT[t] - sum;
    int st0 = excl, st1 = excl + l0, st2 = st1 + l1, st3 = st2 + l2;
    int* sp = segStart + (size_t)blk * SEGP + base;
    sp[0] = st0; sp[1] = st1; sp[2] = st2; sp[3] = st3;
    hist[base] = st0; hist[base + 1] = st1; hist[base + 2] = st2; hist[base + 3] = st3;
    if (t == 255) segStart[(size_t)blk * SEGP + NBIN] = cnt;
    __syncthreads();

    // scatter into staging via LDS cursors
    for (int j = 0; j < nloc; ++j) {
      int slot = atomicAdd(&hist[bins[j]], 1);
      int2 ent;
      ent.x = __float_as_int(vv[j]);
      ent.y = metas[j];
      stage[slot] = ent;
    }
    __syncthreads();

    // coalesced run write (32 KB)
    for (int i = t; i < cnt; i += 256) bucket[s + i] = stage[i];
  } else {
    // cvtX: 256 blocks x 256 threads x 8 elems = 128 x 4096
    int g = (blk - nw) * 256 + t;
    int n = g >> 9;
    int k0 = (g & 511) * 8;
    float4 f0 = *(const float4*)(X + (size_t)n * INF + k0);
    float4 f1 = *(const float4*)(X + (size_t)n * INF + k0 + 4);
    f16x8 h;
    h[0] = (_Float16)f0.x; h[1] = (_Float16)f0.y;
    h[2] = (_Float16)f0.z; h[3] = (_Float16)f0.w;
    h[4] = (_Float16)f1.x; h[5] = (_Float16)f1.y;
    h[6] = (_Float16)f1.z; h[7] = (_Float16)f1.w;
    size_t idx = ((size_t)(k0 >> 5) * 8 + (n >> 4)) * 512 + (n & 15) * 32 + (k0 & 31);
    *(f16x8*)(Xh + idx) = h;
  }
}

// ---- fused densify+GEMM per bin: drain dense bucket segments into a
// 16x1024 fp32 LDS strip (LDS atomics), MFMA vs tiled Xh, reduce 4 wave
// partials through LDS -> slab kq. LDS 65.8 KB -> 2 blocks/CU.
// Drain: 1 chunk per thread (nw=256), one segStart pair + ~4 contiguous
// entry loads, all independent -> short latency chain, high TLP.
// Fragment maps (HW-validated R5/R6): A row=l&15,k=(l>>4)*8+j;
// B col=l&15,same k; C/D col=l&15,row=(l>>4)*4+i.
__global__ __launch_bounds__(256, 2) void k_strip(const int2* __restrict__ bucket,
                                                  const int* __restrict__ segStart,
                                                  int nw,
                                                  const _Float16* __restrict__ Xh,
                                                  float* __restrict__ outP) {
  __shared__ float strip[16 * SQ];  // 65,792 B
  const int t = threadIdx.x;
  const int bin = blockIdx.x;
  const int mt = bin >> 2, kq = bin & 3;

  {  // zero
    float4 z = {0.f, 0.f, 0.f, 0.f};
    const int nvec = 16 * SQ / 4;  // 4112
    for (int j = t; j < nvec; j += 256) ((float4*)strip)[j] = z;
  }
  __syncthreads();

  // drain
  for (int cc = t; cc < nw; cc += 256) {
    const int* sp = segStart + (size_t)cc * SEGP + bin;
    int sb = sp[0];
    int se = sp[1];
    const int2* p = bucket + (size_t)cc * CHUNK;
    for (int j = sb; j < se; ++j) {
      int2 e = p[j];
      atomicAdd(&strip[((e.y >> 10) & 15) * SQ + (e.y & 1023)], __int_as_float(e.x));
    }
  }
  __syncthreads();

  // MFMA: wave wid covers ktl = wid, wid+4, ..., 28+wid (8 iters x 8 nt)
  const int lane = t & 63, wid = t >> 6;
  const int lr = lane & 15, lg = lane >> 4;
  f32x4 acc[8] = {};
  for (int ktl = wid; ktl < 32; ktl += 4) {
    const int kt = kq * 32 + ktl;
    float4 alo = *(const float4*)&strip[lr * SQ + ktl * 32 + lg * 8];
    float4 ahi = *(const float4*)&strip[lr * SQ + ktl * 32 + lg * 8 + 4];
    f16x8 a;
    a[0] = (_Float16)alo.x; a[1] = (_Float16)alo.y;
    a[2] = (_Float16)alo.z; a[3] = (_Float16)alo.w;
    a[4] = (_Float16)ahi.x; a[5] = (_Float16)ahi.y;
    a[6] = (_Float16)ahi.z; a[7] = (_Float16)ahi.w;
    const _Float16* bp = Xh + (size_t)kt * 4096 + lr * 32 + lg * 8;
    f16x8 b[8];
#pragma unroll
    for (int nt = 0; nt < 8; ++nt) b[nt] = *(const f16x8*)(bp + nt * 512);
#pragma unroll
    for (int nt = 0; nt < 8; ++nt)
      acc[nt] = __builtin_amdgcn_mfma_f32_16x16x32_f16(a, b[nt], acc[nt], 0, 0, 0);
  }
  __syncthreads();  // strip reads done; reuse LDS as reduce buffer

  float* red = strip;
#pragma unroll
  for (int nt = 0; nt < 8; ++nt)
#pragma unroll
    for (int i = 0; i < 4; ++i)
      red[wid * 2048 + (lg * 4 + i) * 128 + nt * 16 + lr] = acc[nt][i];
  __syncthreads();
  float* op = outP + (size_t)kq * (OUTF * BATCH) + (size_t)mt * 2048;
  for (int e = t; e < 2048; e += 256)
    op[e] = red[e] + red[2048 + e] + red[4096 + e] + red[6144 + e];
}

// ---- merge 4 slabs [slab][4096 r][128 b] -> out[b][r], LDS transpose ----
__global__ __launch_bounds__(1024) void k_merge(const float* __restrict__ outP,
                                                float* __restrict__ out) {
  __shared__ float t[32][33];
  int bbase = blockIdx.x * 32;
  int rbase = blockIdx.y * 32;
  size_t src = (size_t)(rbase + threadIdx.y) * 128 + bbase + threadIdx.x;
  float s = outP[src] + outP[(size_t)OUTF * BATCH + src] +
            outP[(size_t)2 * OUTF * BATCH + src] + outP[(size_t)3 * OUTF * BATCH + src];
  t[threadIdx.y][threadIdx.x] = s;
  __syncthreads();
  out[(size_t)(bbase + threadIdx.y) * OUTF + rbase + threadIdx.x] = t[threadIdx.x][threadIdx.y];
}

// ---- safety-net fallback if ws is too small: direct atomics ----
__global__ __launch_bounds__(256) void k_fallback(const float* __restrict__ X,
                                                  const float* __restrict__ vals,
                                                  const int* __restrict__ rows,
                                                  const int* __restrict__ cols, int n,
                                                  float* __restrict__ out) {
  int k = blockIdx.x * blockDim.x + threadIdx.x;
  if (k >= n) return;
  float v = vals[k];
  int r = rows[k], c = cols[k];
  for (int b = 0; b < BATCH; ++b)
    atomicAdd(&out[(size_t)b * OUTF + r], v * X[(size_t)b * INF + c]);
}

extern "C" void kernel_launch(void* const* d_in, const int* in_sizes, int n_in,
                              void* d_out, int out_size, void* d_ws, size_t ws_size,
                              hipStream_t stream) {
  const float* X  = (const float*)d_in[0];
  const float* Wv = (const float*)d_in[1];
  const int*   Wr = (const int*)d_in[2];
  const int*   Wc = (const int*)d_in[3];
  float* out = (float*)d_out;
  const int nnz = in_sizes[1];
  const int nw = (nnz + CHUNK - 1) / CHUNK;  // 256 for nnz = 1M

  char* ws = (char*)d_ws;
  const size_t OFF_XH   = 0;                                       // 1 MB
  const size_t OFF_BKT  = OFF_XH  + (size_t)BATCH * INF * 2;       // nnz*8 = 8 MB
  const size_t OFF_SEG  = OFF_BKT + (size_t)(nw * CHUNK) * 8;      // nw*SEGP*4 ~ 1.05 MB
  const size_t OFF_OUTP = OFF_SEG + (size_t)nw * SEGP * 4;         // 8 MB
  const size_t NEEDED   = OFF_OUTP + (size_t)4 * OUTF * BATCH * 4; // ~18 MB

  if (ws_size < NEEDED) {
    hipMemsetAsync(d_out, 0, (size_t)out_size * 4, stream);
    k_fallback<<<dim3((nnz + 255) / 256), dim3(256), 0, stream>>>(X, Wv, Wr, Wc, nnz, out);
    return;
  }

  _Float16* Xh       = (_Float16*)(ws + OFF_XH);
  int2*     bucket   = (int2*)(ws + OFF_BKT);
  int*      segStart = (int*)(ws + OFF_SEG);
  float*    outP     = (float*)(ws + OFF_OUTP);

  k_prep<<<dim3(nw + 256), dim3(256), 0, stream>>>(X, Wv, Wr, Wc, nnz, nw, Xh, bucket, segStart);
  k_strip<<<dim3(NBIN), dim3(256), 0, stream>>>(bucket, segStart, nw, Xh, outP);
  k_merge<<<dim3(BATCH / 32, OUTF / 32), dim3(32, 32), 0, stream>>>(outP, out);
}

// Round 13
// 109.778 us; speedup vs baseline: 1.1135x; 1.0050x over previous
//
#include <hip/hip_runtime.h>
#include <hip/hip_bf16.h>

#define OUTF 4096
#define INF  4096
#define BATCH 128
#define NBIN 1024     // (mt: 256) x (kq: 4)
#define CHUNK 4096    // entries per writer block (lambda=4 per (chunk,bin))
#define SEGP (NBIN + 1)
#define SQ   1028     // strip row stride (1024 + 4 pad)

typedef _Float16 f16x8 __attribute__((ext_vector_type(8)));
typedef float    f32x4 __attribute__((ext_vector_type(4)));

// Xh fp16 tiled: [kt(128)][nt(8)][n(16)][k(32)] -> tile = 512 halfs = 1KB

// ---- fused: blocks [0,nw) sort their 4096-entry COO chunk by bin (dense
// bucket); blocks [nw, nw+256) convert X -> tiled fp16.
// Full chunks take the unrolled register path (rule #20: compile-time
// indices keep the 16-entry working set in VGPRs, not scratch).
__global__ __launch_bounds__(256) void k_prep(const float* __restrict__ X,
                                              const float* __restrict__ vals,
                                              const int* __restrict__ rows,
                                              const int* __restrict__ cols,
                                              int nnz, int nw,
                                              _Float16* __restrict__ Xh,
                                              int2* __restrict__ bucket,
                                              int* __restrict__ segStart) {
  __shared__ int  hist[NBIN];     // 4 KB (becomes cursor)
  __shared__ int  scanT[256];     // 1 KB
  __shared__ int2 stage[CHUNK];   // 32 KB
  const int t = threadIdx.x;
  const int blk = blockIdx.x;

  if (blk < nw) {
    const int s = blk * CHUNK;
    const int e = min(nnz, s + CHUNK);
    const int cnt = e - s;
    for (int b = t; b < NBIN; b += 256) hist[b] = 0;
    __syncthreads();

    int   bins[16], metas[16];
    float vv[16];

    if (cnt == CHUNK) {
      // ---- fast path: fully unrolled, all indices compile-time ----
#pragma unroll
      for (int j = 0; j < 4; ++j) {
        const int g = (s >> 2) + j * 256 + t;
        int4   r4 = ((const int4*)rows)[g];
        int4   c4 = ((const int4*)cols)[g];
        float4 v4 = ((const float4*)vals)[g];
        bins[j * 4 + 0]  = ((r4.x >> 4) << 2) | (c4.x >> 10);
        bins[j * 4 + 1]  = ((r4.y >> 4) << 2) | (c4.y >> 10);
        bins[j * 4 + 2]  = ((r4.z >> 4) << 2) | (c4.z >> 10);
        bins[j * 4 + 3]  = ((r4.w >> 4) << 2) | (c4.w >> 10);
        metas[j * 4 + 0] = ((r4.x & 15) << 10) | (c4.x & 1023);
        metas[j * 4 + 1] = ((r4.y & 15) << 10) | (c4.y & 1023);
        metas[j * 4 + 2] = ((r4.z & 15) << 10) | (c4.z & 1023);
        metas[j * 4 + 3] = ((r4.w & 15) << 10) | (c4.w & 1023);
        vv[j * 4 + 0] = v4.x; vv[j * 4 + 1] = v4.y;
        vv[j * 4 + 2] = v4.z; vv[j * 4 + 3] = v4.w;
#pragma unroll
        for (int q = 0; q < 4; ++q) atomicAdd(&hist[bins[j * 4 + q]], 1);
      }
    } else {
      // ---- ragged tail path (generic, rarely taken) ----
      int nloc = 0;
      for (int i = s + 4 * t; i < min(e, s + 4 * t + 4); ++i) {
        int r = rows[i], c = cols[i];
        bins[nloc]  = ((r >> 4) << 2) | (c >> 10);
        metas[nloc] = ((r & 15) << 10) | (c & 1023);
        vv[nloc] = vals[i];
        atomicAdd(&hist[bins[nloc]], 1);
        ++nloc;
      }
      for (int j = nloc; j < 16; ++j) bins[j] = -1;
    }
    __syncthreads();

    // scan over 1024 bins: thread t owns bins 4t..4t+3
    const int base = t * 4;
    int l0 = hist[base], l1 = hist[base + 1], l2 = hist[base + 2], l3 = hist[base + 3];
    int sum = l0 + l1 + l2 + l3;
    scanT[t] = sum;
    __syncthreads();
    for (int off = 1; off < 256; off <<= 1) {
      int u = (t >= off) ? scanT[t - off] : 0;
      __syncthreads();
      scanT[t] += u;
      __syncthreads();
    }
    int excl = scanT[t] - sum;
    int st0 = excl, st1 = excl + l0, st2 = st1 + l1, st3 = st2 + l2;
    int* sp = segStart + (size_t)blk * SEGP + base;
    sp[0] = st0; sp[1] = st1; sp[2] = st2; sp[3] = st3;
    hist[base] = st0; hist[base + 1] = st1; hist[base + 2] = st2; hist[base + 3] = st3;
    if (t == 255) segStart[(size_t)blk * SEGP + NBIN] = cnt;
    __syncthreads();

    // scatter into staging via LDS cursors (unrolled, static indices)
    if (cnt == CHUNK) {
#pragma unroll
      for (int j = 0; j < 16; ++j) {
        int slot = atomicAdd(&hist[bins[j]], 1);
        int2 ent;
        ent.x = __float_as_int(vv[j]);
        ent.y = metas[j];
        stage[slot] = ent;
      }
    } else {
      for (int j = 0; j < 16; ++j) {
        if (bins[j] < 0) break;
        int slot = atomicAdd(&hist[bins[j]], 1);
        int2 ent;
        ent.x = __float_as_int(vv[j]);
        ent.y = metas[j];
        stage[slot] = ent;
      }
    }
    __syncthreads();

    // coalesced run write (32 KB)
    for (int i = t; i < cnt; i += 256) bucket[s + i] = stage[i];
  } else {
    // cvtX: 256 blocks x 256 threads x 8 elems = 128 x 4096
    int g = (blk - nw) * 256 + t;
    int n = g >> 9;
    int k0 = (g & 511) * 8;
    float4 f0 = *(const float4*)(X + (size_t)n * INF + k0);
    float4 f1 = *(const float4*)(X + (size_t)n * INF + k0 + 4);
    f16x8 h;
    h[0] = (_Float16)f0.x; h[1] = (_Float16)f0.y;
    h[2] = (_Float16)f0.z; h[3] = (_Float16)f0.w;
    h[4] = (_Float16)f1.x; h[5] = (_Float16)f1.y;
    h[6] = (_Float16)f1.z; h[7] = (_Float16)f1.w;
    size_t idx = ((size_t)(k0 >> 5) * 8 + (n >> 4)) * 512 + (n & 15) * 32 + (k0 & 31);
    *(f16x8*)(Xh + idx) = h;
  }
}

// ---- transpose segStart [nw][SEGP] -> segT [SEGP][nw] so k_strip reads
// its 256 per-chunk bounds as two contiguous 1KB rows (was: 1 line / 4B).
__global__ __launch_bounds__(1024) void k_segT(const int* __restrict__ segStart,
                                               int* __restrict__ segT, int nw) {
  __shared__ int tile[32][33];
  int b0 = blockIdx.x * 32;   // bin base (SEGP rows -> 33 tiles)
  int c0 = blockIdx.y * 32;   // chunk base (nw cols -> nw/32 tiles)
  int bin = b0 + threadIdx.y;
  if (bin < SEGP)
    tile[threadIdx.y][threadIdx.x] = segStart[(size_t)(c0 + threadIdx.x) * SEGP + bin];
  __syncthreads();
  int obin = b0 + threadIdx.x;
  if (obin < SEGP)
    segT[(size_t)obin * nw + c0 + threadIdx.y] = tile[threadIdx.x][threadIdx.y];
}

// ---- fused densify+GEMM per bin: drain dense bucket segments into a
// 16x1024 fp32 LDS strip (LDS atomics), MFMA vs tiled Xh, reduce 4 wave
// partials through LDS -> slab kq. LDS 65.8 KB -> 2 blocks/CU.
// Fragment maps (HW-validated R5/R6): A row=l&15,k=(l>>4)*8+j;
// B col=l&15,same k; C/D col=l&15,row=(l>>4)*4+i.
__global__ __launch_bounds__(256, 2) void k_strip(const int2* __restrict__ bucket,
                                                  const int* __restrict__ segT,
                                                  int nw,
                                                  const _Float16* __restrict__ Xh,
                                                  float* __restrict__ outP) {
  __shared__ float strip[16 * SQ];  // 65,792 B
  const int t = threadIdx.x;
  const int bin = blockIdx.x;
  const int mt = bin >> 2, kq = bin & 3;

  {  // zero
    float4 z = {0.f, 0.f, 0.f, 0.f};
    const int nvec = 16 * SQ / 4;  // 4112
    for (int j = t; j < nvec; j += 256) ((float4*)strip)[j] = z;
  }
  __syncthreads();

  // drain: thread t owns chunk cc=t (+256 stride); bounds reads coalesced
  for (int cc = t; cc < nw; cc += 256) {
    int sb = segT[(size_t)bin * nw + cc];
    int se = segT[(size_t)(bin + 1) * nw + cc];
    const int2* p = bucket + (size_t)cc * CHUNK;
    for (int j = sb; j < se; ++j) {
      int2 e = p[j];
      atomicAdd(&strip[((e.y >> 10) & 15) * SQ + (e.y & 1023)], __int_as_float(e.x));
    }
  }
  __syncthreads();

  // MFMA: wave wid covers ktl = wid, wid+4, ..., 28+wid (8 iters x 8 nt)
  const int lane = t & 63, wid = t >> 6;
  const int lr = lane & 15, lg = lane >> 4;
  f32x4 acc[8] = {};
  for (int ktl = wid; ktl < 32; ktl += 4) {
    const int kt = kq * 32 + ktl;
    float4 alo = *(const float4*)&strip[lr * SQ + ktl * 32 + lg * 8];
    float4 ahi = *(const float4*)&strip[lr * SQ + ktl * 32 + lg * 8 + 4];
    f16x8 a;
    a[0] = (_Float16)alo.x; a[1] = (_Float16)alo.y;
    a[2] = (_Float16)alo.z; a[3] = (_Float16)alo.w;
    a[4] = (_Float16)ahi.x; a[5] = (_Float16)ahi.y;
    a[6] = (_Float16)ahi.z; a[7] = (_Float16)ahi.w;
    const _Float16* bp = Xh + (size_t)kt * 4096 + lr * 32 + lg * 8;
    f16x8 b[8];
#pragma unroll
    for (int nt = 0; nt < 8; ++nt) b[nt] = *(const f16x8*)(bp + nt * 512);
#pragma unroll
    for (int nt = 0; nt < 8; ++nt)
      acc[nt] = __builtin_amdgcn_mfma_f32_16x16x32_f16(a, b[nt], acc[nt], 0, 0, 0);
  }
  __syncthreads();  // strip reads done; reuse LDS as reduce buffer

  float* red = strip;
#pragma unroll
  for (int nt = 0; nt < 8; ++nt)
#pragma unroll
    for (int i = 0; i < 4; ++i)
      red[wid * 2048 + (lg * 4 + i) * 128 + nt * 16 + lr] = acc[nt][i];
  __syncthreads();
  float* op = outP + (size_t)kq * (OUTF * BATCH) + (size_t)mt * 2048;
  for (int e = t; e < 2048; e += 256)
    op[e] = red[e] + red[2048 + e] + red[4096 + e] + red[6144 + e];
}

// ---- merge 4 slabs [slab][4096 r][128 b] -> out[b][r], LDS transpose ----
__global__ __launch_bounds__(1024) void k_merge(const float* __restrict__ outP,
                                                float* __restrict__ out) {
  __shared__ float t[32][33];
  int bbase = blockIdx.x * 32;
  int rbase = blockIdx.y * 32;
  size_t src = (size_t)(rbase + threadIdx.y) * 128 + bbase + threadIdx.x;
  float s = outP[src] + outP[(size_t)OUTF * BATCH + src] +
            outP[(size_t)2 * OUTF * BATCH + src] + outP[(size_t)3 * OUTF * BATCH + src];
  t[threadIdx.y][threadIdx.x] = s;
  __syncthreads();
  out[(size_t)(bbase + threadIdx.y) * OUTF + rbase + threadIdx.x] = t[threadIdx.x][threadIdx.y];
}

// ---- safety-net fallback if ws is too small: direct atomics ----
__global__ __launch_bounds__(256) void k_fallback(const float* __restrict__ X,
                                                  const float* __restrict__ vals,
                                                  const int* __restrict__ rows,
                                                  const int* __restrict__ cols, int n,
                                                  float* __restrict__ out) {
  int k = blockIdx.x * blockDim.x + threadIdx.x;
  if (k >= n) return;
  float v = vals[k];
  int r = rows[k], c = cols[k];
  for (int b = 0; b < BATCH; ++b)
    atomicAdd(&out[(size_t)b * OUTF + r], v * X[(size_t)b * INF + c]);
}

extern "C" void kernel_launch(void* const* d_in, const int* in_sizes, int n_in,
                              void* d_out, int out_size, void* d_ws, size_t ws_size,
                              hipStream_t stream) {
  const float* X  = (const float*)d_in[0];
  const float* Wv = (const float*)d_in[1];
  const int*   Wr = (const int*)d_in[2];
  const int*   Wc = (const int*)d_in[3];
  float* out = (float*)d_out;
  const int nnz = in_sizes[1];
  const int nw = (nnz + CHUNK - 1) / CHUNK;  // 256 for nnz = 1M

  char* ws = (char*)d_ws;
  const size_t OFF_XH   = 0;                                       // 1 MB
  const size_t OFF_BKT  = OFF_XH  + (size_t)BATCH * INF * 2;       // nnz*8 = 8 MB
  const size_t OFF_SEG  = OFF_BKT + (size_t)(nw * CHUNK) * 8;      // nw*SEGP*4 ~ 1.05 MB
  const size_t OFF_SEGT = OFF_SEG + (size_t)nw * SEGP * 4;         // SEGP*nw*4 ~ 1.05 MB
  const size_t OFF_OUTP = OFF_SEGT + (size_t)SEGP * nw * 4;        // 8 MB
  const size_t NEEDED   = OFF_OUTP + (size_t)4 * OUTF * BATCH * 4; // ~19 MB

  if (ws_size < NEEDED || (nw & 31) != 0) {
    hipMemsetAsync(d_out, 0, (size_t)out_size * 4, stream);
    k_fallback<<<dim3((nnz + 255) / 256), dim3(256), 0, stream>>>(X, Wv, Wr, Wc, nnz, out);
    return;
  }

  _Float16* Xh       = (_Float16*)(ws + OFF_XH);
  int2*     bucket   = (int2*)(ws + OFF_BKT);
  int*      segStart = (int*)(ws + OFF_SEG);
  int*      segT     = (int*)(ws + OFF_SEGT);
  float*    outP     = (float*)(ws + OFF_OUTP);

  k_prep<<<dim3(nw + 256), dim3(256), 0, stream>>>(X, Wv, Wr, Wc, nnz, nw, Xh, bucket, segStart);
  k_segT<<<dim3((SEGP + 31) / 32, nw / 32), dim3(32, 32), 0, stream>>>(segStart, segT, nw);
  k_strip<<<dim3(NBIN), dim3(256), 0, stream>>>(bucket, segT, nw, Xh, outP);
  k_merge<<<dim3(BATCH / 32, OUTF / 32), dim3(32, 32), 0, stream>>>(outP, out);
}